// Round 7
// baseline (739.411 us; speedup 1.0000x reference)
//
#include <hip/hip_runtime.h>
#include <hip/hip_bf16.h>
#include <cmath>

#define DEVFN __device__ __forceinline__

typedef __attribute__((ext_vector_type(8))) short short8;
typedef __attribute__((ext_vector_type(4))) float f32x4;

constexpr int C_DIM   = 1024;
constexpr int E_NUM   = 8;
constexpr int DFF_DIM = 4096;
constexpr int NTOK    = 8192;       // B*T
constexpr int PAD     = 256;        // expert segment alignment
constexpr int MAXROWS = NTOK * 2 + E_NUM * PAD;  // 18432

DEVFN unsigned short f2bf(float f) {
    __hip_bfloat16 h = __float2bfloat16(f);
    return __builtin_bit_cast(unsigned short, h);
}
DEVFN void gload_lds16(const void* g, void* lds) {
    __builtin_amdgcn_global_load_lds(
        (const __attribute__((address_space(1))) unsigned int*)g,
        (__attribute__((address_space(3))) unsigned int*)lds, 16, 0, 0);
}

// meta layout (ints): [0..7] counts, [8..15] cursor, [16..24] offs (offs[8]=padTotal)

__global__ void init_kernel(int* meta, int* rowtok) {
    int gid = blockIdx.x * 256 + threadIdx.x;
    if (gid < 64) meta[gid] = 0;
    if (gid < MAXROWS) rowtok[gid] = 0;
}

// One-time: wg[c][e], wn[c][e] -> wT[o][c] (o<8: gate, o>=8: noise). 16K elems.
__global__ void wrouter_T_kernel(const float* __restrict__ wg, const float* __restrict__ wn,
                                 float* __restrict__ wT) {
    int i = blockIdx.x * 256 + threadIdx.x;  // 16384
    int o = i >> 10, c = i & 1023;
    wT[i] = (o < 8) ? wg[c * 8 + o] : wn[c * 8 + (o - 8)];
}

// Router: 32 tokens/block, 8 threads/token. Coalesced x float4 loads,
// broadcast wT loads, fp64 accumulation (exact products, fp64 adds).
__global__ __launch_bounds__(256) void router_kernel(
    const float* __restrict__ x, const float* __restrict__ noise,
    const float* __restrict__ wT, const float* __restrict__ bg,
    const float* __restrict__ bn, int* meta, int2* tok_e, float2* tok_w) {
    int tid = threadIdx.x;
    int tt = tid >> 3, sub = tid & 7;
    int tok = blockIdx.x * 32 + tt;
    const float* xr = x + (size_t)tok * C_DIM;

    double acc[16];
#pragma unroll
    for (int o = 0; o < 16; o++) acc[o] = 0.0;

#pragma unroll 4
    for (int i = 0; i < 32; i++) {
        int c = i * 32 + sub * 4;
        float4 xv = *(const float4*)(xr + c);
#pragma unroll
        for (int o = 0; o < 16; o++) {
            float4 wv = *(const float4*)(wT + o * C_DIM + c);
            acc[o] += (double)xv.x * (double)wv.x;
            acc[o] += (double)xv.y * (double)wv.y;
            acc[o] += (double)xv.z * (double)wv.z;
            acc[o] += (double)xv.w * (double)wv.w;
        }
    }
#pragma unroll
    for (int s = 1; s <= 4; s <<= 1) {
#pragma unroll
        for (int o = 0; o < 16; o++) acc[o] += __shfl_xor(acc[o], s, 64);
    }
    if (sub == 0) {
        double logit[8];
#pragma unroll
        for (int e = 0; e < 8; e++) {
            double cl = acc[e] + (double)bg[e];
            double nl = acc[8 + e] + (double)bn[e];
            double sp = (nl > 30.0) ? nl : log1p(exp(nl));
            logit[e] = cl + (double)noise[(size_t)tok * 8 + e] * sp;
        }
        int i1 = -1, i2 = -1;
        double v1 = -1e300, v2 = -1e300;
#pragma unroll
        for (int e = 0; e < 8; e++) {
            double v = logit[e];
            if (v > v1) { v2 = v1; i2 = i1; v1 = v; i1 = e; }
            else if (v > v2) { v2 = v; i2 = e; }
        }
        double d = exp(v2 - v1);
        tok_e[tok] = make_int2(i1, i2);
        tok_w[tok] = make_float2((float)(1.0 / (1.0 + d)), (float)(d / (1.0 + d)));
        atomicAdd(&meta[i1], 1);
        atomicAdd(&meta[i2], 1);
    }
}

__global__ void offsets_kernel(int* meta) {
    if (threadIdx.x == 0 && blockIdx.x == 0) {
        int off = 0;
        for (int e = 0; e < 8; e++) {
            meta[16 + e] = off;
            off += (meta[e] + PAD - 1) / PAD * PAD;
            meta[8 + e] = 0;  // cursor
        }
        meta[24] = off;  // padTotal
    }
}

// Wave-aggregated slot assignment (atomic order doesn't affect any FP result).
__global__ void assign_kernel(int* meta, const int2* tok_e,
                              int2* tok_pos, int* rowtok) {
    int t = blockIdx.x * 256 + threadIdx.x;
    int lane = threadIdx.x & 63;
    int2 e = tok_e[t];
    int sel[2] = {e.x, e.y};
    int pos[2];
#pragma unroll
    for (int s = 0; s < 2; s++) {
        int p = 0;
#pragma unroll
        for (int ex = 0; ex < 8; ex++) {
            unsigned long long m = __ballot(sel[s] == ex);
            if (m) {
                int leader = __ffsll((unsigned long long)m) - 1;
                int base = 0;
                if (lane == leader) base = atomicAdd(&meta[8 + ex], (int)__popcll(m));
                base = __shfl(base, leader, 64);
                if (sel[s] == ex)
                    p = meta[16 + ex] + base + (int)__popcll(m & ((1ull << lane) - 1ull));
            }
        }
        pos[s] = p;
        rowtok[p] = t;
    }
    tok_pos[t] = make_int2(pos[0], pos[1]);
}

// Gather token rows into packed order, fp32 -> bf16.
__global__ void gather_x_kernel(const float* __restrict__ x, const int* __restrict__ rowtok,
                                unsigned short* __restrict__ Xg) {
    int p = blockIdx.x;
    int tok = rowtok[p];
    const float4* src = (const float4*)(x + (size_t)tok * C_DIM);
    ushort4* dst = (ushort4*)(Xg + (size_t)p * C_DIM);
    int i = threadIdx.x;  // 256 threads x 4 elems = 1024
    float4 v = src[i];
    ushort4 o;
    o.x = f2bf(v.x); o.y = f2bf(v.y); o.z = f2bf(v.z); o.w = f2bf(v.w);
    dst[i] = o;
}

// [E][R][S] fp32 -> [E][S][R] bf16, 64x64 tiles, vectorized both sides.
__global__ __launch_bounds__(256) void transpose_bf16_kernel(
    const float* __restrict__ in, unsigned short* __restrict__ out, int R, int S) {
    __shared__ float tile[64][68];
    const float* ine = in + (size_t)blockIdx.z * R * S;
    unsigned short* oute = out + (size_t)blockIdx.z * R * S;
    int s0 = blockIdx.x * 64, r0 = blockIdx.y * 64;
    int tid = threadIdx.x;
    int rr = tid >> 2, cs = (tid & 3) * 16;
    const float4* src = (const float4*)(ine + (size_t)(r0 + rr) * S + s0 + cs);
#pragma unroll
    for (int q = 0; q < 4; q++) *(float4*)&tile[rr][cs + q * 4] = src[q];
    __syncthreads();
    int ss = tid >> 2, rs = (tid & 3) * 16;
    ushort4 o[4];
#pragma unroll
    for (int q = 0; q < 4; q++) {
        ushort4 v;
        v.x = f2bf(tile[rs + q * 4 + 0][ss]);
        v.y = f2bf(tile[rs + q * 4 + 1][ss]);
        v.z = f2bf(tile[rs + q * 4 + 2][ss]);
        v.w = f2bf(tile[rs + q * 4 + 3][ss]);
        o[q] = v;
    }
    ushort4* dst = (ushort4*)(oute + (size_t)(s0 + ss) * R + r0 + rs);
#pragma unroll
    for (int q = 0; q < 4; q++) dst[q] = o[q];
}

// ---------------------------------------------------------------------------
// 8-phase 256x256 GEMM, 512 thr = 8 waves (2M x 4N), BK=64, dbuf x2.
// R7: register-dbuf fragment prefetch (each quad's ds_reads issue under the
// previous quad's MFMAs), kk-outer MFMA order (dep distance 8), base+imm
// ds_read addressing. Stage stream + counted vmcnt identical to R6.
// ---------------------------------------------------------------------------
template <int KDIM, int KLEN, int NDIM, int MODE>
__global__ __launch_bounds__(512, 2) void gemm8_kernel(
    const unsigned short* __restrict__ A, const unsigned short* __restrict__ Bt,
    const float* __restrict__ bias, unsigned short* __restrict__ OutH,
    float* __restrict__ OutC0, float* __restrict__ OutC1,
    const int* __restrict__ meta) {
    extern __shared__ char ldsraw[];  // 131072 bytes

    int nwg = gridDim.x;
    int orig = blockIdx.x;
    int q = nwg >> 3, r8 = nwg & 7;
    int xcd = orig & 7, idx = orig >> 3;
    int wgid = (xcd < r8 ? xcd * (q + 1) : r8 * (q + 1) + (xcd - r8) * q) + idx;
    constexpr int NCT = NDIM / 256;
    int rowBase = (wgid / NCT) * 256;
    int colBase = (wgid % NCT) * 256;
    if (rowBase >= meta[24]) return;
    int e = 0;
#pragma unroll
    for (int i = 1; i < 8; i++)
        if (rowBase >= meta[16 + i]) e = i;
    int koff = blockIdx.z * KLEN;

    int tid = threadIdx.x;
    int wv = tid >> 6, lane = tid & 63;
    int wr = wv >> 2, wcol = wv & 3;  // 2M x 4N waves; wave output 128x64

    const unsigned short* Ab = A + (size_t)rowBase * KDIM + koff;
    const unsigned short* Bb = Bt + (size_t)e * NDIM * KDIM + (size_t)colBase * KDIM + koff;

    int rA = tid >> 3;
    int sSl = ((tid & 7) ^ (rA & 7)) * 8;
    const unsigned short* pA0 = Ab + (size_t)rA * KDIM + sSl;
    const unsigned short* pB0 = Bb + (size_t)rA * KDIM + sSl;

#define STAGEA(bufoff, half, t) { \
        char* d_ = ldsraw + (bufoff) + (half) * 16384 + wv * 1024; \
        const unsigned short* s_ = pA0 + (size_t)(half) * (128 * KDIM) + (size_t)(t) * 64; \
        gload_lds16(s_, d_); \
        gload_lds16(s_ + (size_t)64 * KDIM, d_ + 8192); }
#define STAGEB(bufoff, half, t) { \
        char* d_ = ldsraw + (bufoff) + 32768 + (half) * 16384 + wv * 1024; \
        const unsigned short* s_ = pB0 + (size_t)(half) * (128 * KDIM) + (size_t)(t) * 64; \
        gload_lds16(s_, d_); \
        gload_lds16(s_ + (size_t)64 * KDIM, d_ + 8192); }

    // Fragment base addresses (swizzled), constant imm offsets per m/n.
    int physk0 = (lane >> 4) ^ (lane & 7);
    int kdel = ((physk0 ^ 4) - physk0) * 16;  // +-64
    const char* aB0k0 = ldsraw + wr * 16384 + (lane & 15) * 128 + physk0 * 16;
    const char* aB0k1 = aB0k0 + kdel;
    const char* bB0k0 = ldsraw + 32768 + (wcol >> 1) * 16384 +
                        ((wcol & 1) * 64 + (lane & 15)) * 128 + physk0 * 16;
    const char* bB0k1 = bB0k0 + kdel;
    const char* aB1k0 = aB0k0 + 65536;
    const char* aB1k1 = aB0k1 + 65536;
    const char* bB1k0 = bB0k0 + 65536;
    const char* bB1k1 = bB0k1 + 65536;

    short8 afA[4][2], afB[4][2], bfA[2][2], bfB[2][2];
    f32x4 acc[8][4];
#pragma unroll
    for (int m = 0; m < 8; m++)
#pragma unroll
        for (int n = 0; n < 4; n++) acc[m][n] = f32x4{0.f, 0.f, 0.f, 0.f};

#define LDA(DST, K0, K1, MOFF) \
    _Pragma("unroll") for (int mm = 0; mm < 4; mm++) { \
        DST[mm][0] = *(const short8*)((K0) + ((MOFF) + mm) * 2048); \
        DST[mm][1] = *(const short8*)((K1) + ((MOFF) + mm) * 2048); }
#define LDB(DST, K0, K1, NOFF) \
    _Pragma("unroll") for (int nn = 0; nn < 2; nn++) { \
        DST[nn][0] = *(const short8*)((K0) + ((NOFF) + nn) * 2048); \
        DST[nn][1] = *(const short8*)((K1) + ((NOFF) + nn) * 2048); }
#define QUAD(AF, BF, MB, NB) \
    __builtin_amdgcn_s_setprio(1); \
    _Pragma("unroll") for (int kk = 0; kk < 2; kk++) \
    _Pragma("unroll") for (int mm = 0; mm < 4; mm++) \
    _Pragma("unroll") for (int nn = 0; nn < 2; nn++) \
        acc[(MB) + mm][(NB) + nn] = __builtin_amdgcn_mfma_f32_16x16x32_bf16( \
            AF[mm][kk], BF[nn][kk], acc[(MB) + mm][(NB) + nn], 0, 0, 0); \
    __builtin_amdgcn_s_setprio(0);
#define SB() __builtin_amdgcn_sched_barrier(0)
#define BAR() { SB(); __builtin_amdgcn_s_barrier(); SB(); }

    constexpr int T = KLEN / 64;
    static_assert(T % 2 == 0, "T even");
    constexpr int ITERS = T / 2;

    // Prologue: tile0 all 4 halves + tile1 B halves.
    STAGEB(0, 0, 0) STAGEB(0, 1, 0) STAGEA(0, 0, 0) STAGEA(0, 1, 0)
    STAGEB(65536, 0, 1) STAGEB(65536, 1, 1)
    SB(); asm volatile("s_waitcnt vmcnt(4)" ::: "memory"); SB();
    __builtin_amdgcn_s_barrier(); SB();

#pragma unroll 1
    for (int i = 0; i < ITERS; ++i) {
        int t0 = 2 * i;
        bool last = (i == ITERS - 1);
        // ---- K-tile t0 (buf0) ----
        // P1: Q1 frags + Q2's B-frags (latter complete under Q1's MFMAs)
        LDA(afA, aB0k0, aB0k1, 0) LDB(bfA, bB0k0, bB0k1, 0)
        STAGEA(65536, 0, t0 + 1)
        BAR();
        LDB(bfB, bB0k0, bB0k1, 2)
        QUAD(afA, bfA, 0, 0)
        BAR();
        // P2: Q3's A-frags complete under Q2's MFMAs
        STAGEA(65536, 1, t0 + 1)
        BAR();
        LDA(afB, aB0k0, aB0k1, 4)
        QUAD(afA, bfB, 0, 2)
        BAR();
        // P3
        if (!last) STAGEB(0, 0, t0 + 2)
        BAR();
        QUAD(afB, bfA, 4, 0)
        BAR();
        // P4
        if (!last) STAGEB(0, 1, t0 + 2)
        SB(); __builtin_amdgcn_s_barrier(); SB();
        QUAD(afB, bfB, 4, 2)
        SB();
        if (last) { asm volatile("s_waitcnt vmcnt(0)" ::: "memory"); }
        else      { asm volatile("s_waitcnt vmcnt(4)" ::: "memory"); }
        BAR();
        // ---- K-tile t0+1 (buf1) ----
        // P5
        LDA(afA, aB1k0, aB1k1, 0) LDB(bfA, bB1k0, bB1k1, 0)
        if (!last) STAGEA(0, 0, t0 + 2)
        BAR();
        LDB(bfB, bB1k0, bB1k1, 2)
        QUAD(afA, bfA, 0, 0)
        BAR();
        // P6
        if (!last) STAGEA(0, 1, t0 + 2)
        BAR();
        LDA(afB, aB1k0, aB1k1, 4)
        QUAD(afA, bfB, 0, 2)
        BAR();
        // P7
        if (!last) STAGEB(65536, 0, t0 + 3)
        BAR();
        QUAD(afB, bfA, 4, 0)
        BAR();
        // P8
        if (!last) STAGEB(65536, 1, t0 + 3)
        SB(); __builtin_amdgcn_s_barrier(); SB();
        QUAD(afB, bfB, 4, 2)
        SB();
        if (!last) { asm volatile("s_waitcnt vmcnt(4)" ::: "memory"); }
        BAR();
    }
#undef STAGEA
#undef STAGEB
#undef LDA
#undef LDB
#undef QUAD

    // Epilogue.
    float bv[4];
#pragma unroll
    for (int n = 0; n < 4; n++)
        bv[n] = bias[(size_t)e * NDIM + colBase + wcol * 64 + n * 16 + (lane & 15)];

    if constexpr (MODE == 1) {
        // relu -> bf16, repack via LDS with rr-XOR swizzle, coalesced 16B stores.
        unsigned short* lds16 = (unsigned short*)ldsraw;
#pragma unroll
        for (int m = 0; m < 8; m++) {
#pragma unroll
            for (int n = 0; n < 4; n++) {
#pragma unroll
                for (int j = 0; j < 4; j++) {
                    float v = fmaxf(acc[m][n][j] + bv[n], 0.f);
                    int rr = wr * 128 + m * 16 + (lane >> 4) * 4 + j;
                    int cc = wcol * 64 + n * 16 + (lane & 15);
                    lds16[rr * 256 + (cc ^ ((rr & 7) << 4))] = f2bf(v);
                }
            }
        }
        __syncthreads();
        int row = tid >> 1, half = tid & 1;
        int xr = (row & 7) << 4;
#pragma unroll
        for (int i = 0; i < 16; i++) {
            int cs = half * 128 + i * 8;
            short8 val = *(const short8*)(lds16 + row * 256 + (cs ^ xr));
            *(short8*)(OutH + (size_t)(rowBase + row) * NDIM + colBase + cs) = val;
        }
    } else {
        float* Of = (blockIdx.z == 0) ? OutC0 : OutC1;
        if (blockIdx.z != 0) {
#pragma unroll
            for (int n = 0; n < 4; n++) bv[n] = 0.f;
        }
#pragma unroll
        for (int m = 0; m < 8; m++) {
#pragma unroll
            for (int n = 0; n < 4; n++) {
#pragma unroll
                for (int j = 0; j < 4; j++) {
                    int rr = wr * 128 + m * 16 + (lane >> 4) * 4 + j;
                    int cc = wcol * 64 + n * 16 + (lane & 15);
                    Of[(size_t)(rowBase + rr) * NDIM + colBase + cc] = acc[m][n][j] + bv[n];
                }
            }
        }
    }
}

// out[t] = w0*(c0[p0]+c1[p0]) + w1*(c0[p1]+c1[p1])  (fixed order, deterministic)
__global__ void combine_kernel(const float* __restrict__ c0, const float* __restrict__ c1,
                               const int2* __restrict__ tok_pos, const float2* __restrict__ tok_w,
                               float* __restrict__ out) {
    int t = blockIdx.x;
    int2 p = tok_pos[t];
    float2 w = tok_w[t];
    int i = threadIdx.x;
    float4 a0 = ((const float4*)(c0 + (size_t)p.x * C_DIM))[i];
    float4 a1 = ((const float4*)(c1 + (size_t)p.x * C_DIM))[i];
    float4 b0 = ((const float4*)(c0 + (size_t)p.y * C_DIM))[i];
    float4 b1 = ((const float4*)(c1 + (size_t)p.y * C_DIM))[i];
    float4 r;
    r.x = w.x * (a0.x + a1.x) + w.y * (b0.x + b1.x);
    r.y = w.x * (a0.y + a1.y) + w.y * (b0.y + b1.y);
    r.z = w.x * (a0.z + a1.z) + w.y * (b0.z + b1.z);
    r.w = w.x * (a0.w + a1.w) + w.y * (b0.w + b1.w);
    ((float4*)(out + (size_t)t * C_DIM))[i] = r;
}

extern "C" void kernel_launch(void* const* d_in, const int* in_sizes, int n_in,
                              void* d_out, int out_size, void* d_ws, size_t ws_size,
                              hipStream_t stream) {
    (void)in_sizes; (void)n_in; (void)out_size; (void)ws_size;
    const float* x       = (const float*)d_in[0];
    const float* noise   = (const float*)d_in[1];
    const float* w_gate  = (const float*)d_in[2];
    const float* b_gate  = (const float*)d_in[3];
    const float* w_noise = (const float*)d_in[4];
    const float* b_noise = (const float*)d_in[5];
    const float* w1      = (const float*)d_in[6];
    const float* b1      = (const float*)d_in[7];
    const float* w2      = (const float*)d_in[8];
    const float* b2      = (const float*)d_in[9];
    float* out = (float*)d_out;

    char* w = (char*)d_ws;
    size_t off = 0;
    int* meta = (int*)(w + off); off += 256;
    float* wT = (float*)(w + off); off += 16 * C_DIM * 4;
    int2* tok_e = (int2*)(w + off); off += (size_t)NTOK * 8;
    float2* tok_w = (float2*)(w + off); off += (size_t)NTOK * 8;
    int2* tok_pos = (int2*)(w + off); off += (size_t)NTOK * 8;
    int* rowtok = (int*)(w + off); off += (size_t)MAXROWS * 4;
    unsigned short* H = (unsigned short*)(w + off); off += (size_t)MAXROWS * DFF_DIM * 2;
    unsigned short* w2b = (unsigned short*)(w + off); off += (size_t)E_NUM * C_DIM * DFF_DIM * 2;
    float* c0 = (float*)(w + off); off += (size_t)MAXROWS * C_DIM * 4;
    unsigned short* Xg = (unsigned short*)(w + off); off += (size_t)MAXROWS * C_DIM * 2;
    unsigned short* w1b = (unsigned short*)(w + off); off += (size_t)E_NUM * DFF_DIM * C_DIM * 2;
    // c1 aliases [Xg, Xg + 75.5MB): Xg/w1b are dead once gemm1 has run, and
    // both are fully rewritten by gather/transpose on every call (replay-safe).
    float* c1 = (float*)Xg;

    init_kernel<<<(MAXROWS + 255) / 256, 256, 0, stream>>>(meta, rowtok);
    wrouter_T_kernel<<<64, 256, 0, stream>>>(w_gate, w_noise, wT);
    router_kernel<<<NTOK / 32, 256, 0, stream>>>(x, noise, wT, b_gate, b_noise,
                                                 meta, tok_e, tok_w);
    offsets_kernel<<<1, 64, 0, stream>>>(meta);
    assign_kernel<<<NTOK / 256, 256, 0, stream>>>(meta, tok_e, tok_pos, rowtok);
    gather_x_kernel<<<MAXROWS, 256, 0, stream>>>(x, rowtok, Xg);
    transpose_bf16_kernel<<<dim3(DFF_DIM / 64, C_DIM / 64, E_NUM), 256, 0, stream>>>(w1, w1b, C_DIM, DFF_DIM);
    transpose_bf16_kernel<<<dim3(C_DIM / 64, DFF_DIM / 64, E_NUM), 256, 0, stream>>>(w2, w2b, DFF_DIM, C_DIM);

    hipFuncSetAttribute((const void*)gemm8_kernel<C_DIM, C_DIM, DFF_DIM, 1>,
                        hipFuncAttributeMaxDynamicSharedMemorySize, 131072);
    gemm8_kernel<C_DIM, C_DIM, DFF_DIM, 1>
        <<<dim3((MAXROWS / 256) * (DFF_DIM / 256), 1, 1), 512, 131072, stream>>>(
            Xg, w1b, b1, H, nullptr, nullptr, meta);

    hipFuncSetAttribute((const void*)gemm8_kernel<DFF_DIM, DFF_DIM / 2, C_DIM, 2>,
                        hipFuncAttributeMaxDynamicSharedMemorySize, 131072);
    gemm8_kernel<DFF_DIM, DFF_DIM / 2, C_DIM, 2>
        <<<dim3((MAXROWS / 256) * (C_DIM / 256), 1, 2), 512, 131072, stream>>>(
            H, w2b, b2, nullptr, c0, c1, meta);

    combine_kernel<<<NTOK, 256, 0, stream>>>(c0, c1, tok_pos, tok_w, out);
}